// Round 1
// baseline (279.379 us; speedup 1.0000x reference)
//
#include <hip/hip_runtime.h>
#include <hip/hip_bf16.h>

typedef __bf16 bf16x8 __attribute__((ext_vector_type(8)));
typedef float f32x4 __attribute__((ext_vector_type(4)));

#define B_ 2
#define T_ 2048
#define EMB_ 1024
#define H_ 16
#define D_ 64
#define M_ (B_ * T_)        // 4096
#define NQKV_ (3 * H_ * D_) // 3072

// ---------------- cast x fp32 -> bf16 ----------------
__global__ void cast_bf16_k(const float* __restrict__ in, __bf16* __restrict__ out) {
    int i = (blockIdx.x * blockDim.x + threadIdx.x) * 8;
    float4 a = *reinterpret_cast<const float4*>(in + i);
    float4 b = *reinterpret_cast<const float4*>(in + i + 4);
    bf16x8 o;
    o[0] = (__bf16)a.x; o[1] = (__bf16)a.y; o[2] = (__bf16)a.z; o[3] = (__bf16)a.w;
    o[4] = (__bf16)b.x; o[5] = (__bf16)b.y; o[6] = (__bf16)b.z; o[7] = (__bf16)b.w;
    *reinterpret_cast<bf16x8*>(out + i) = o;
}

// ---------------- transpose + cast: in [K][N] fp32 -> out [N][K] bf16 ----------------
__global__ void transpose_cast_k(const float* __restrict__ in, __bf16* __restrict__ out,
                                 int K, int N) {
    __shared__ float tile[32][33];
    int bx = blockIdx.x;  // over N
    int by = blockIdx.y;  // over K
    int tx = threadIdx.x, ty = threadIdx.y;  // 32 x 8
    for (int j = 0; j < 32; j += 8)
        tile[ty + j][tx] = in[(size_t)(by * 32 + ty + j) * N + bx * 32 + tx];
    __syncthreads();
    for (int j = 0; j < 32; j += 8)
        out[(size_t)(bx * 32 + ty + j) * K + by * 32 + tx] = (__bf16)tile[tx][ty + j];
}

// ---------------- GEMM: A[M][K] bf16, Bt[N][K] bf16, bias fp32 ----------------
// EPI 0: outF[row][col] = acc + bias  (fp32)
// EPI 1: qkv scatter -> Qg/Kg [b,h,t,d] bf16, Vtg [b,h,d,t] bf16
#define BM 128
#define BN 128
#define BK 64
#define LDP (BK + 8)

template <int EPI>
__global__ __launch_bounds__(256, 2) void gemm_bf16_k(
    const __bf16* __restrict__ A, const __bf16* __restrict__ Bt,
    const float* __restrict__ bias, float* __restrict__ outF,
    __bf16* __restrict__ Qg, __bf16* __restrict__ Kg, __bf16* __restrict__ Vtg,
    int Mdim, int Ndim, int Kdim) {
    __shared__ __bf16 As[BM][LDP];
    __shared__ __bf16 Bs[BN][LDP];
    const int tid = threadIdx.x;
    const int lane = tid & 63;
    const int w = tid >> 6;
    const int wr = w >> 1, wc = w & 1;
    const int row0 = blockIdx.y * BM;
    const int col0 = blockIdx.x * BN;
    const int lr = lane & 15;
    const int lg = lane >> 4;

    f32x4 acc[4][4] = {};

    for (int k0 = 0; k0 < Kdim; k0 += BK) {
        // stage A and Bt tiles: 128 rows x 64 cols each; 1024 16B-chunks per tile
        for (int i = 0; i < 4; ++i) {
            int chunk = i * 256 + tid;          // 0..1023
            int r = chunk >> 3;                 // 0..127
            int c = (chunk & 7) * 8;            // 0..56
            *reinterpret_cast<bf16x8*>(&As[r][c]) =
                *reinterpret_cast<const bf16x8*>(&A[(size_t)(row0 + r) * Kdim + k0 + c]);
            *reinterpret_cast<bf16x8*>(&Bs[r][c]) =
                *reinterpret_cast<const bf16x8*>(&Bt[(size_t)(col0 + r) * Kdim + k0 + c]);
        }
        __syncthreads();
        for (int kk = 0; kk < BK; kk += 32) {
            bf16x8 af[4], bfr[4];
            for (int mt = 0; mt < 4; ++mt)
                af[mt] = *reinterpret_cast<const bf16x8*>(&As[wr * 64 + mt * 16 + lr][kk + lg * 8]);
            for (int nt = 0; nt < 4; ++nt)
                bfr[nt] = *reinterpret_cast<const bf16x8*>(&Bs[wc * 64 + nt * 16 + lr][kk + lg * 8]);
            for (int mt = 0; mt < 4; ++mt)
                for (int nt = 0; nt < 4; ++nt)
                    acc[mt][nt] = __builtin_amdgcn_mfma_f32_16x16x32_bf16(
                        af[mt], bfr[nt], acc[mt][nt], 0, 0, 0);
        }
        __syncthreads();
    }

    for (int mt = 0; mt < 4; ++mt)
        for (int nt = 0; nt < 4; ++nt)
            for (int r = 0; r < 4; ++r) {
                int row = row0 + wr * 64 + mt * 16 + lg * 4 + r;
                int col = col0 + wc * 64 + nt * 16 + lr;
                float v = acc[mt][nt][r] + bias[col];
                if (EPI == 0) {
                    outF[(size_t)row * Ndim + col] = v;
                } else {
                    int part = col >> 10;
                    int hh = (col >> 6) & 15;
                    int dd = col & 63;
                    int bb = row >> 11;
                    int tt = row & 2047;
                    __bf16 bv = (__bf16)v;
                    size_t bh = (size_t)(bb * H_ + hh);
                    if (part == 0)
                        Qg[(bh * T_ + tt) * D_ + dd] = bv;
                    else if (part == 1)
                        Kg[(bh * T_ + tt) * D_ + dd] = bv;
                    else
                        Vtg[(bh * D_ + dd) * T_ + tt] = bv;
                }
            }
}

// ---------------- causal flash attention ----------------
// Qg,Kg: [b,h,t,d] bf16 ; Vtg: [b,h,d,t] bf16 ; Og: [b*t][h*64+d] bf16
#define QBLK 128
#define KVBLK 64

__global__ __launch_bounds__(256, 2) void attn_k(
    const __bf16* __restrict__ Qg, const __bf16* __restrict__ Kg,
    const __bf16* __restrict__ Vtg, __bf16* __restrict__ Og) {
    __shared__ __bf16 Ks[KVBLK][72];       // [kv][d]
    __shared__ __bf16 Vs[D_][72];          // [d][kv]  (transposed V)
    __shared__ __bf16 Ps[4][32][72];       // per-wave P tile [qrow][kv]

    const int tid = threadIdx.x;
    const int lane = tid & 63;
    const int w = tid >> 6;
    const int lr = lane & 15;
    const int lg = lane >> 4;
    const int q0 = blockIdx.x * QBLK;
    const int bh = blockIdx.y;                 // b*H + h
    const size_t baseQK = (size_t)bh * T_ * D_;
    const size_t baseVt = (size_t)bh * D_ * T_;
    const int qw = q0 + w * 32;                // this wave's first q row

    // Q fragments in registers: 2 row-tiles x 2 k-steps
    bf16x8 qf[2][2];
    for (int mt = 0; mt < 2; ++mt)
        for (int ks = 0; ks < 2; ++ks)
            qf[mt][ks] = *reinterpret_cast<const bf16x8*>(
                &Qg[baseQK + (size_t)(qw + mt * 16 + lr) * D_ + ks * 32 + lg * 8]);

    f32x4 oacc[2][4] = {};
    float mrow[2][4], lrow[2][4];
    for (int mt = 0; mt < 2; ++mt)
        for (int r = 0; r < 4; ++r) { mrow[mt][r] = -1e30f; lrow[mt][r] = 0.f; }

    const int ntile = (q0 + QBLK) / KVBLK;
    for (int t = 0; t < ntile; ++t) {
        const int kv0 = t * KVBLK;
        // stage K tile [64][64] and transposed-V tile [64][64]
        for (int i = 0; i < 2; ++i) {
            int chunk = i * 256 + tid;   // 0..511
            int r = chunk >> 3;          // 0..63
            int c = (chunk & 7) * 8;     // 0..56
            *reinterpret_cast<bf16x8*>(&Ks[r][c]) =
                *reinterpret_cast<const bf16x8*>(&Kg[baseQK + (size_t)(kv0 + r) * D_ + c]);
            *reinterpret_cast<bf16x8*>(&Vs[r][c]) =
                *reinterpret_cast<const bf16x8*>(&Vtg[baseVt + (size_t)r * T_ + kv0 + c]);
        }
        __syncthreads();

        if (kv0 <= qw + 31) {   // wave-uniform: any unmasked element for this wave?
            // S = Q K^T
            f32x4 s[2][4] = {};
            for (int kk = 0; kk < 2; ++kk) {
                bf16x8 kf[4];
                for (int nt = 0; nt < 4; ++nt)
                    kf[nt] = *reinterpret_cast<const bf16x8*>(&Ks[nt * 16 + lr][kk * 32 + lg * 8]);
                for (int mt = 0; mt < 2; ++mt)
                    for (int nt = 0; nt < 4; ++nt)
                        s[mt][nt] = __builtin_amdgcn_mfma_f32_16x16x32_bf16(
                            qf[mt][kk], kf[nt], s[mt][nt], 0, 0, 0);
            }
            const bool needmask = (kv0 + 63 > qw);
            for (int mt = 0; mt < 2; ++mt)
                for (int nt = 0; nt < 4; ++nt)
                    for (int r = 0; r < 4; ++r) {
                        float sv = s[mt][nt][r] * 0.125f;  // 1/sqrt(64)
                        if (needmask) {
                            int qi = qw + mt * 16 + lg * 4 + r;
                            int ki = kv0 + nt * 16 + lr;
                            if (ki > qi) sv = -1e30f;
                        }
                        s[mt][nt][r] = sv;
                    }
            // online softmax per q-row
            for (int mt = 0; mt < 2; ++mt)
                for (int r = 0; r < 4; ++r) {
                    float mx = fmaxf(fmaxf(s[mt][0][r], s[mt][1][r]),
                                     fmaxf(s[mt][2][r], s[mt][3][r]));
                    for (int off = 1; off < 16; off <<= 1)
                        mx = fmaxf(mx, __shfl_xor(mx, off, 64));
                    float mnew = fmaxf(mrow[mt][r], mx);
                    float corr = __expf(mrow[mt][r] - mnew);
                    mrow[mt][r] = mnew;
                    float psum = 0.f;
                    for (int nt = 0; nt < 4; ++nt) {
                        float p = __expf(s[mt][nt][r] - mnew);
                        s[mt][nt][r] = p;
                        psum += p;
                    }
                    for (int off = 1; off < 16; off <<= 1)
                        psum += __shfl_xor(psum, off, 64);
                    lrow[mt][r] = lrow[mt][r] * corr + psum;
                    for (int nt = 0; nt < 4; ++nt) oacc[mt][nt][r] *= corr;
                }
            // P -> per-wave LDS (D-layout -> A-frag layout round-trip)
            for (int mt = 0; mt < 2; ++mt)
                for (int nt = 0; nt < 4; ++nt)
                    for (int r = 0; r < 4; ++r)
                        Ps[w][mt * 16 + lg * 4 + r][nt * 16 + lr] = (__bf16)s[mt][nt][r];
            asm volatile("s_waitcnt lgkmcnt(0)" ::: "memory");
            // O += P V
            for (int ks = 0; ks < 2; ++ks) {
                bf16x8 vf[4], pf[2];
                for (int nt = 0; nt < 4; ++nt)
                    vf[nt] = *reinterpret_cast<const bf16x8*>(&Vs[nt * 16 + lr][ks * 32 + lg * 8]);
                for (int mt = 0; mt < 2; ++mt)
                    pf[mt] = *reinterpret_cast<const bf16x8*>(&Ps[w][mt * 16 + lr][ks * 32 + lg * 8]);
                for (int mt = 0; mt < 2; ++mt)
                    for (int nt = 0; nt < 4; ++nt)
                        oacc[mt][nt] = __builtin_amdgcn_mfma_f32_16x16x32_bf16(
                            pf[mt], vf[nt], oacc[mt][nt], 0, 0, 0);
            }
        }
        __syncthreads();
    }

    // write O: [b*t][h*64+d] bf16
    const int b = bh >> 4, h = bh & 15;
    for (int mt = 0; mt < 2; ++mt)
        for (int nt = 0; nt < 4; ++nt)
            for (int r = 0; r < 4; ++r) {
                int tt = qw + mt * 16 + lg * 4 + r;
                int dd = nt * 16 + lr;
                float v = oacc[mt][nt][r] / lrow[mt][r];
                Og[(size_t)(b * T_ + tt) * (H_ * D_) + h * D_ + dd] = (__bf16)v;
            }
}

// ---------------- launch ----------------
extern "C" void kernel_launch(void* const* d_in, const int* in_sizes, int n_in,
                              void* d_out, int out_size, void* d_ws, size_t ws_size,
                              hipStream_t stream) {
    const float* x    = (const float*)d_in[0];
    const float* Wqkv = (const float*)d_in[1];
    const float* bqkv = (const float*)d_in[2];
    const float* Wout = (const float*)d_in[3];
    const float* bout = (const float*)d_in[4];
    float* outF = (float*)d_out;

    char* ws = (char*)d_ws;
    __bf16* xb     = (__bf16*)(ws);                       // 4096x1024
    __bf16* WqkvT  = (__bf16*)(ws + 8388608);             // 3072x1024
    __bf16* WoutT  = (__bf16*)(ws + 14680064);            // 1024x1024
    __bf16* Qg     = (__bf16*)(ws + 16777216);            // [b,h,t,d]
    __bf16* Kg     = (__bf16*)(ws + 25165824);            // [b,h,t,d]
    __bf16* Vtg    = (__bf16*)(ws + 33554432);            // [b,h,d,t]
    __bf16* Og     = (__bf16*)(ws + 41943040);            // [b*t][h*d]

    // casts / transposes
    cast_bf16_k<<<(M_ * EMB_) / (256 * 8), 256, 0, stream>>>(x, xb);
    transpose_cast_k<<<dim3(NQKV_ / 32, EMB_ / 32), dim3(32, 8), 0, stream>>>(Wqkv, WqkvT, EMB_, NQKV_);
    transpose_cast_k<<<dim3(EMB_ / 32, EMB_ / 32), dim3(32, 8), 0, stream>>>(Wout, WoutT, EMB_, EMB_);

    // QKV projection (+scatter to heads)
    gemm_bf16_k<1><<<dim3(NQKV_ / BN, M_ / BM), 256, 0, stream>>>(
        xb, WqkvT, bqkv, nullptr, Qg, Kg, Vtg, M_, NQKV_, EMB_);

    // causal flash attention
    attn_k<<<dim3(T_ / QBLK, B_ * H_), 256, 0, stream>>>(Qg, Kg, Vtg, Og);

    // output projection
    gemm_bf16_k<0><<<dim3(EMB_ / BN, M_ / BM), 256, 0, stream>>>(
        Og, WoutT, bout, outF, nullptr, nullptr, nullptr, M_, EMB_, EMB_);
}

// Round 2
// 208.538 us; speedup vs baseline: 1.3397x; 1.3397x over previous
//
#include <hip/hip_runtime.h>
#include <hip/hip_bf16.h>

typedef __bf16 bf16x8 __attribute__((ext_vector_type(8)));
typedef float f32x4 __attribute__((ext_vector_type(4)));
typedef float f32x16 __attribute__((ext_vector_type(16)));
typedef unsigned int uint32x4v __attribute__((ext_vector_type(4)));

#define B_ 2
#define T_ 2048
#define EMB_ 1024
#define H_ 16
#define D_ 64
#define M_ (B_ * T_)        // 4096
#define NQKV_ (3 * H_ * D_) // 3072

#define GPTR(p) ((const __attribute__((address_space(1))) unsigned int*)(p))
#define LPTR(p) ((__attribute__((address_space(3))) unsigned int*)(p))

__device__ __forceinline__ unsigned pk2(float a, float b) {
    unsigned short ua = __builtin_bit_cast(unsigned short, (__bf16)a);
    unsigned short ub = __builtin_bit_cast(unsigned short, (__bf16)b);
    return (unsigned)ua | ((unsigned)ub << 16);
}

// ---------------- cast x fp32 -> bf16 ----------------
__global__ void cast_bf16_k(const float* __restrict__ in, __bf16* __restrict__ out) {
    int i = (blockIdx.x * blockDim.x + threadIdx.x) * 8;
    float4 a = *reinterpret_cast<const float4*>(in + i);
    float4 b = *reinterpret_cast<const float4*>(in + i + 4);
    bf16x8 o;
    o[0] = (__bf16)a.x; o[1] = (__bf16)a.y; o[2] = (__bf16)a.z; o[3] = (__bf16)a.w;
    o[4] = (__bf16)b.x; o[5] = (__bf16)b.y; o[6] = (__bf16)b.z; o[7] = (__bf16)b.w;
    *reinterpret_cast<bf16x8*>(out + i) = o;
}

// ---------------- transpose + cast: in [K][N] fp32 -> out [N][K] bf16 ----------------
__global__ void transpose_cast_k(const float* __restrict__ in, __bf16* __restrict__ out,
                                 int K, int N) {
    __shared__ float tile[32][33];
    int bx = blockIdx.x;  // over N
    int by = blockIdx.y;  // over K
    int tx = threadIdx.x, ty = threadIdx.y;  // 32 x 8
    for (int j = 0; j < 32; j += 8)
        tile[ty + j][tx] = in[(size_t)(by * 32 + ty + j) * N + bx * 32 + tx];
    __syncthreads();
    for (int j = 0; j < 32; j += 8)
        out[(size_t)(bx * 32 + ty + j) * K + by * 32 + tx] = (__bf16)tile[tx][ty + j];
}

// ---------------- GEMM: A[M][K] bf16, Bt[N][K] bf16, bias fp32 ----------------
// m97 structure: linear LDS [128][64], global_load_lds width=16 staging.
#define BM 128
#define BN 128
#define BK 64

template <int EPI>
__global__ __launch_bounds__(256, 2) void gemm_bf16_k(
    const __bf16* __restrict__ A, const __bf16* __restrict__ Bt,
    const float* __restrict__ bias, float* __restrict__ outF,
    __bf16* __restrict__ Qg, __bf16* __restrict__ Kg, __bf16* __restrict__ Vtg,
    int Mdim, int Ndim, int Kdim) {
    __shared__ __bf16 As[BM * BK];
    __shared__ __bf16 Bs[BN * BK];
    const int tid = threadIdx.x;
    const int lane = tid & 63;
    const int w = tid >> 6;
    const int wr = w >> 1, wc = w & 1;
    const int row0 = blockIdx.y * BM;
    const int col0 = blockIdx.x * BN;
    const int lr = lane & 15;
    const int lg = lane >> 4;

    f32x4 acc[4][4] = {};

    for (int k0 = 0; k0 < Kdim; k0 += BK) {
        // stage: each wave stages 32 rows of A and 32 rows of B (4 instrs each)
        #pragma unroll
        for (int i = 0; i < 4; ++i) {
            int r0 = 32 * w + 8 * i;
            int row = r0 + (lane >> 3);
            int c8 = (lane & 7) * 8;
            __builtin_amdgcn_global_load_lds(
                GPTR(A + (size_t)(row0 + row) * Kdim + k0 + c8), LPTR(&As[r0 * BK]), 16, 0, 0);
            __builtin_amdgcn_global_load_lds(
                GPTR(Bt + (size_t)(col0 + row) * Kdim + k0 + c8), LPTR(&Bs[r0 * BK]), 16, 0, 0);
        }
        __syncthreads();
        #pragma unroll
        for (int kk = 0; kk < BK; kk += 32) {
            bf16x8 af[4], bfr[4];
            #pragma unroll
            for (int mt = 0; mt < 4; ++mt)
                af[mt] = *reinterpret_cast<const bf16x8*>(&As[(wr * 64 + mt * 16 + lr) * BK + kk + lg * 8]);
            #pragma unroll
            for (int nt = 0; nt < 4; ++nt)
                bfr[nt] = *reinterpret_cast<const bf16x8*>(&Bs[(wc * 64 + nt * 16 + lr) * BK + kk + lg * 8]);
            #pragma unroll
            for (int mt = 0; mt < 4; ++mt)
                #pragma unroll
                for (int nt = 0; nt < 4; ++nt)
                    acc[mt][nt] = __builtin_amdgcn_mfma_f32_16x16x32_bf16(
                        af[mt], bfr[nt], acc[mt][nt], 0, 0, 0);
        }
        __syncthreads();
    }

    #pragma unroll
    for (int mt = 0; mt < 4; ++mt)
        #pragma unroll
        for (int nt = 0; nt < 4; ++nt)
            #pragma unroll
            for (int r = 0; r < 4; ++r) {
                int row = row0 + wr * 64 + mt * 16 + lg * 4 + r;
                int col = col0 + wc * 64 + nt * 16 + lr;
                float v = acc[mt][nt][r] + bias[col];
                if (EPI == 0) {
                    outF[(size_t)row * Ndim + col] = v;
                } else {
                    int part = col >> 10;
                    int hh = (col >> 6) & 15;
                    int dd = col & 63;
                    int bb = row >> 11;
                    int tt = row & 2047;
                    __bf16 bv = (__bf16)v;
                    size_t bh = (size_t)(bb * H_ + hh);
                    if (part == 0)
                        Qg[(bh * T_ + tt) * D_ + dd] = bv;
                    else if (part == 1)
                        Kg[(bh * T_ + tt) * D_ + dd] = bv;
                    else
                        Vtg[(bh * D_ + dd) * T_ + tt] = bv;
                }
            }
}

// ---------------- causal flash attention (swapped-QK^T, 32x32 MFMA) ----------------
// Qg,Kg: [b,h,t,d] bf16 ; Vtg: [b,h,d,t] bf16 ; Og: [b*t][h*64+d] bf16
// 4 waves x 32 q-rows = QBLK 128; KVBLK 64; K/V LDS XOR-chunk-swizzled.
#define KVB 64

__global__ __launch_bounds__(256, 2) void attn_k(
    const __bf16* __restrict__ Qg, const __bf16* __restrict__ Kg,
    const __bf16* __restrict__ Vtg, __bf16* __restrict__ Og) {
    __shared__ __bf16 Ks[KVB * 64];   // [kv][d], 16B chunks swizzled: chunk ^= row&7
    __shared__ __bf16 Vs[64 * 64];    // [d][kv], same swizzle

    const int tid = threadIdx.x;
    const int lane = tid & 63;
    const int w = tid >> 6;          // 0..3
    const int l31 = lane & 31;
    const int hi = lane >> 5;

    const int id = blockIdx.x;       // 0..511
    const int bh = id & 31;
    const int qb = (id < 256) ? (15 - (id >> 5)) : ((id - 256) >> 5);
    const size_t baseQK = (size_t)bh * T_ * D_;
    const size_t baseVt = (size_t)bh * D_ * T_;
    const int qw = qb * 128 + w * 32;      // this wave's first q row
    const int q_lane = qw + l31;           // this lane's q row (S^T column)

    // Q B-frags: qf[ks] holds Q[q_lane][16ks + 8hi .. +8]
    bf16x8 qf[4];
    #pragma unroll
    for (int ks = 0; ks < 4; ++ks)
        qf[ks] = *reinterpret_cast<const bf16x8*>(
            &Qg[baseQK + (size_t)q_lane * D_ + ks * 16 + hi * 8]);

    f32x16 o0 = {}, o1 = {};   // O[q][d]: col d = dt*32 + l31, row q = (r&3)+8*(r>>2)+4*hi
    float m = -1e30f, lsum = 0.f;

    const int ntile = 2 * qb + 2;
    for (int t = 0; t < ntile; ++t) {
        const int kv0 = t * KVB;
        // ---- stage K,V: linear LDS dest, pre-swizzled global source (m173) ----
        #pragma unroll
        for (int i = 0; i < 2; ++i) {
            int r0 = 16 * w + 8 * i;
            int row = r0 + (lane >> 3);
            int c = (lane & 7) ^ (row & 7);
            __builtin_amdgcn_global_load_lds(
                GPTR(Kg + baseQK + (size_t)(kv0 + row) * D_ + 8 * c),
                LPTR(&Ks[r0 * 64]), 16, 0, 0);
            __builtin_amdgcn_global_load_lds(
                GPTR(Vtg + baseVt + (size_t)row * T_ + kv0 + 8 * c),
                LPTR(&Vs[r0 * 64]), 16, 0, 0);
        }
        __syncthreads();

        if (kv0 < qw + 32) {
            // ---- S^T = K Q^T : two 32-kv accs ----
            f32x16 s0 = {}, s1 = {};
            #pragma unroll
            for (int ks = 0; ks < 4; ++ks) {
                int c = (((2 * ks + hi) ^ (l31 & 7)) * 8);
                bf16x8 kf0 = *reinterpret_cast<const bf16x8*>(&Ks[l31 * 64 + c]);
                bf16x8 kf1 = *reinterpret_cast<const bf16x8*>(&Ks[(32 + l31) * 64 + c]);
                s0 = __builtin_amdgcn_mfma_f32_32x32x16_bf16(kf0, qf[ks], s0, 0, 0, 0);
                s1 = __builtin_amdgcn_mfma_f32_32x32x16_bf16(kf1, qf[ks], s1, 0, 0, 0);
            }
            // ---- scale + causal mask (in-register) ----
            const bool diag = (kv0 + KVB > qw);   // wave-uniform
            if (diag) {
                #pragma unroll
                for (int r = 0; r < 16; ++r) {
                    int kvr = kv0 + (r & 3) + 8 * (r >> 2) + 4 * hi;
                    s0[r] = (kvr <= q_lane) ? s0[r] * 0.125f : -1e30f;
                    s1[r] = (kvr + 32 <= q_lane) ? s1[r] * 0.125f : -1e30f;
                }
            } else {
                #pragma unroll
                for (int r = 0; r < 16; ++r) { s0[r] *= 0.125f; s1[r] *= 0.125f; }
            }
            // ---- row max (in-lane + one cross-half) ----
            float pmax = -1e30f;
            #pragma unroll
            for (int r = 0; r < 16; ++r)
                pmax = fmaxf(pmax, fmaxf(s0[r], s1[r]));
            pmax = fmaxf(pmax, __shfl_xor(pmax, 32, 64));
            // ---- defer-max rescale (THR=8) ----
            if (__any(pmax > m + 8.f)) {
                float mnew = fmaxf(m, pmax);
                float corr = __expf(m - mnew);
                m = mnew;
                lsum *= corr;
                #pragma unroll
                for (int r = 0; r < 16; ++r) {
                    int qsrc = (r & 3) + 8 * (r >> 2) + 4 * hi;
                    float cb = __shfl(corr, qsrc, 64);
                    o0[r] *= cb; o1[r] *= cb;
                }
            }
            // ---- P = exp(S - m), row sum ----
            float ps = 0.f;
            #pragma unroll
            for (int r = 0; r < 16; ++r) {
                s0[r] = __expf(s0[r] - m);
                s1[r] = __expf(s1[r] - m);
                ps += s0[r] + s1[r];
            }
            ps += __shfl_xor(ps, 32, 64);
            lsum += ps;
            // ---- P -> bf16 A-frags (cross-half exchange) + PV ----
            #pragma unroll
            for (int ks = 0; ks < 4; ++ks) {
                const int e = (ks & 1) * 8;
                unsigned w0, w1, w2, w3;
                if (ks < 2) {
                    w0 = pk2(s0[e + 0], s0[e + 1]); w1 = pk2(s0[e + 2], s0[e + 3]);
                    w2 = pk2(s0[e + 4], s0[e + 5]); w3 = pk2(s0[e + 6], s0[e + 7]);
                } else {
                    w0 = pk2(s1[e + 0], s1[e + 1]); w1 = pk2(s1[e + 2], s1[e + 3]);
                    w2 = pk2(s1[e + 4], s1[e + 5]); w3 = pk2(s1[e + 6], s1[e + 7]);
                }
                unsigned pw0 = __shfl_xor(w0, 32, 64);
                unsigned pw1 = __shfl_xor(w1, 32, 64);
                unsigned pw2 = __shfl_xor(w2, 32, 64);
                unsigned pw3 = __shfl_xor(w3, 32, 64);
                uint32x4v uf;
                uf.x = hi ? pw2 : w0;
                uf.y = hi ? pw3 : w1;
                uf.z = hi ? w2 : pw0;
                uf.w = hi ? w3 : pw1;
                bf16x8 pa = __builtin_bit_cast(bf16x8, uf);
                int c = (((2 * ks + hi) ^ (l31 & 7)) * 8);
                bf16x8 vf0 = *reinterpret_cast<const bf16x8*>(&Vs[l31 * 64 + c]);
                bf16x8 vf1 = *reinterpret_cast<const bf16x8*>(&Vs[(32 + l31) * 64 + c]);
                o0 = __builtin_amdgcn_mfma_f32_32x32x16_bf16(pa, vf0, o0, 0, 0, 0);
                o1 = __builtin_amdgcn_mfma_f32_32x32x16_bf16(pa, vf1, o1, 0, 0, 0);
            }
        }
        __syncthreads();
    }

    // ---- epilogue: O /= l, write Og[b*t][h*64+d] ----
    const int b = bh >> 4, h = bh & 15;
    float li = 1.0f / lsum;
    #pragma unroll
    for (int r = 0; r < 16; ++r) {
        int qsrc = (r & 3) + 8 * (r >> 2) + 4 * hi;
        float cb = __shfl(li, qsrc, 64);
        int tt = qw + qsrc;
        size_t base = (size_t)(b * T_ + tt) * (H_ * D_) + h * D_;
        Og[base + l31]      = (__bf16)(o0[r] * cb);
        Og[base + 32 + l31] = (__bf16)(o1[r] * cb);
    }
}

// ---------------- launch ----------------
extern "C" void kernel_launch(void* const* d_in, const int* in_sizes, int n_in,
                              void* d_out, int out_size, void* d_ws, size_t ws_size,
                              hipStream_t stream) {
    const float* x    = (const float*)d_in[0];
    const float* Wqkv = (const float*)d_in[1];
    const float* bqkv = (const float*)d_in[2];
    const float* Wout = (const float*)d_in[3];
    const float* bout = (const float*)d_in[4];
    float* outF = (float*)d_out;

    char* ws = (char*)d_ws;
    __bf16* xb     = (__bf16*)(ws);                       // 4096x1024
    __bf16* WqkvT  = (__bf16*)(ws + 8388608);             // 3072x1024
    __bf16* WoutT  = (__bf16*)(ws + 14680064);            // 1024x1024
    __bf16* Qg     = (__bf16*)(ws + 16777216);            // [b,h,t,d]
    __bf16* Kg     = (__bf16*)(ws + 25165824);            // [b,h,t,d]
    __bf16* Vtg    = (__bf16*)(ws + 33554432);            // [b,h,d,t]
    __bf16* Og     = (__bf16*)(ws + 41943040);            // [b*t][h*d]

    // casts / transposes
    cast_bf16_k<<<(M_ * EMB_) / (256 * 8), 256, 0, stream>>>(x, xb);
    transpose_cast_k<<<dim3(NQKV_ / 32, EMB_ / 32), dim3(32, 8), 0, stream>>>(Wqkv, WqkvT, EMB_, NQKV_);
    transpose_cast_k<<<dim3(EMB_ / 32, EMB_ / 32), dim3(32, 8), 0, stream>>>(Wout, WoutT, EMB_, EMB_);

    // QKV projection (+scatter to heads)
    gemm_bf16_k<1><<<dim3(NQKV_ / BN, M_ / BM), 256, 0, stream>>>(
        xb, WqkvT, bqkv, nullptr, Qg, Kg, Vtg, M_, NQKV_, EMB_);

    // causal flash attention (512 blocks, complementary-qb pairing, heavy first)
    attn_k<<<512, 256, 0, stream>>>(Qg, Kg, Vtg, Og);

    // output projection
    gemm_bf16_k<0><<<dim3(EMB_ / BN, M_ / BM), 256, 0, stream>>>(
        Og, WoutT, bout, outF, nullptr, nullptr, nullptr, M_, EMB_, EMB_);
}